// Round 16
// baseline (333.320 us; speedup 1.0000x reference)
//
#include <hip/hip_runtime.h>
#include <hip/hip_bf16.h>
#include <stdint.h>

#define B_  4
#define T_  300
#define U_  60
#define V_  1000
#define M_TOT (B_*T_*U_)   // 72000
#define MB_CNT 563         // ceil(72000/128)
#define CH0 282            // chunk 0 mb count
#define CH1 (MB_CNT - CH0) // chunk 1 mb count (281)
#define WK  1056           // padded W1t row stride (shorts)

typedef __attribute__((ext_vector_type(8))) short short8;
typedef __attribute__((ext_vector_type(4))) float f32x4;
typedef __attribute__((ext_vector_type(4))) int int4v;

__device__ __forceinline__ short f2bf(float f) {
    union { float f; uint32_t u; } c; c.f = f;
    uint32_t u = c.u;
    uint32_t r = (u + 0x7FFFu + ((u >> 16) & 1u)) >> 16;
    return (short)r;
}

__device__ __forceinline__ float b2f(short s) {
    union { float f; uint32_t u; } c;
    c.u = ((uint32_t)(uint16_t)s) << 16;
    return c.f;
}

__device__ __forceinline__ float fast_tanh(float x) {
    float e = __expf(2.0f * x);
    float r = __builtin_amdgcn_rcpf(e + 1.0f);
    return 1.0f - 2.0f * r;
}

__device__ __forceinline__ void gl_lds16(const void* g, void* l) {
    __builtin_amdgcn_global_load_lds(
        (const __attribute__((address_space(1))) void*)g,
        (__attribute__((address_space(3))) void*)l, 16, 0, 0);
}

// ---------------- merged weight prep ----------------
__global__ void prep_weights(const float* __restrict__ W1, const float* __restrict__ W2,
                             short* __restrict__ W1t, short* __restrict__ W2p) {
    __shared__ float tile[64][65];
    const int tx = threadIdx.x & 63, ty = threadIdx.x >> 6;
    const int r0 = blockIdx.y * 64, c0 = blockIdx.x * 64;
    if (blockIdx.z == 0) {
#pragma unroll
        for (int i = 0; i < 16; ++i) {
            int r = r0 + i * 4 + ty, c = c0 + tx;
            tile[i * 4 + ty][tx] = W1[(long)r * 1024 + c];
        }
        __syncthreads();
#pragma unroll
        for (int i = 0; i < 16; ++i) {
            int oc = c0 + i * 4 + ty;
            int orr = r0 + tx;
            W1t[(long)oc * WK + orr] = f2bf(tile[tx][i * 4 + ty]);
        }
    } else {
#pragma unroll
        for (int i = 0; i < 16; ++i) {
            int r = r0 + i * 4 + ty, c = c0 + tx;   // r=k, c=v
            float v = 0.f;
            if (c < V_) v = W2[(long)r * V_ + c];
            tile[i * 4 + ty][tx] = v;
        }
        __syncthreads();
#pragma unroll
        for (int i = 0; i < 16; ++i) {
            int oc = c0 + i * 4 + ty;       // v 0..1023
            int orr = r0 + tx;              // k 0..1023
            int nb = oc >> 8, prow = oc & 255, kt = orr >> 5, ks = orr & 31;
            W2p[(long)(nb * 32 + kt) * 8192 + prow * 32 + ks] = f2bf(tile[tx][i * 4 + ty]);
        }
    }
}

// ---------------- merged projections (bf16 out) ----------------
__global__ __launch_bounds__(256, 2) void proj_both(
        const float* __restrict__ enc, const float* __restrict__ dec,
        const short* __restrict__ Wt, const float* __restrict__ b1,
        short* __restrict__ encB, short* __restrict__ decB)
{
    __shared__ short As[64 * 64];
    const int tid = threadIdx.x;
    const int lane = tid & 63;
    const int w = tid >> 6;
    const int wm = w >> 1, wn = w & 1;

    const int bx = blockIdx.x;
    const bool isenc = bx < 19;
    const float* X  = isenc ? enc : dec;
    const int M     = isenc ? 1200 : 240;
    const int k_off = isenc ? 0 : 512;
    short* P        = isenc ? encB : decB;
    const int m0 = (isenc ? bx : bx - 19) * 64;
    const int n0 = blockIdx.y * 64;

    f32x4 acc[2][2] = {};
    for (int k0 = 0; k0 < 512; k0 += 64) {
#pragma unroll
        for (int c = 0; c < 2; ++c) {
            int lin = tid + 256 * c;
            int row = lin >> 3, k8 = lin & 7;
            int m = m0 + row;
            short vals[8];
            if (m < M) {
                const float* xp = X + (long)m * 512 + k0 + k8 * 8;
#pragma unroll
                for (int j = 0; j < 8; ++j) vals[j] = f2bf(xp[j]);
            } else {
#pragma unroll
                for (int j = 0; j < 8; ++j) vals[j] = 0;
            }
            int byte = row * 128 + k8 * 16;
            byte ^= (row & 7) << 4;
            *(int4v*)((char*)As + byte) = *(const int4v*)vals;
        }
        __syncthreads();
#pragma unroll
        for (int ks = 0; ks < 2; ++ks) {
            short8 af[2];
#pragma unroll
            for (int mf = 0; mf < 2; ++mf) {
                int row = wm * 32 + mf * 16 + (lane & 15);
                int byte = row * 128 + ks * 64 + (lane >> 4) * 16;
                byte ^= (row & 7) << 4;
                af[mf] = *(const short8*)((char*)As + byte);
            }
#pragma unroll
            for (int nf = 0; nf < 2; ++nf) {
                int h = n0 + wn * 32 + nf * 16 + (lane & 15);
                const short* bp = Wt + (long)h * WK + k_off + k0 + ks * 32 + (lane >> 4) * 8;
                short8 bfv = *(const short8*)bp;
#pragma unroll
                for (int mf = 0; mf < 2; ++mf)
                    acc[mf][nf] = __builtin_amdgcn_mfma_f32_16x16x32_bf16(af[mf], bfv, acc[mf][nf], 0, 0, 0);
            }
        }
        __syncthreads();
    }
#pragma unroll
    for (int mf = 0; mf < 2; ++mf)
#pragma unroll
        for (int nf = 0; nf < 2; ++nf) {
            int h = n0 + wn * 32 + nf * 16 + (lane & 15);
            float bb = isenc ? 0.f : b1[h];
#pragma unroll
            for (int j = 0; j < 4; ++j) {
                int m = m0 + wm * 32 + mf * 16 + (lane >> 4) * 4 + j;
                if (m < M) P[(long)m * 1024 + h] = f2bf(acc[mf][nf][j] + bb);
            }
        }
}

// ---------------- packed H, chunked (bf16 inputs) ----------------
__global__ __launch_bounds__(256) void hgen_pk(
        const short* __restrict__ encB, const short* __restrict__ decB,
        short* __restrict__ Hp, int mb_base)
{
    long idx = (long)blockIdx.x * 256 + threadIdx.x;
    int u = (int)(idx >> 9);           // local unit
    int gi = (int)(idx & 511);
    int mbl = u >> 5, kt = u & 31;
    int r = gi >> 2, g = gi & 3;
    int m = (mb_base + mbl) * 128 + r;
    int k = kt * 32 + g * 8;
    short8 v = {};
    if (m < M_TOT) {
        int bt = m / U_;
        int uu = m - bt * U_;
        int b = m / (T_ * U_);
        short8 e = *(const short8*)(encB + (long)bt * 1024 + k);
        short8 d = *(const short8*)(decB + (long)(b * U_ + uu) * 1024 + k);
#pragma unroll
        for (int j = 0; j < 8; ++j)
            v[j] = f2bf(fast_tanh(b2f(e[j]) + b2f(d[j])));
    }
    *(short8*)(Hp + (long)u * 4096 + gi * 8) = v;
}

// ---------------- main GEMM (chunked, nontemporal output stores) ----------
// BM=128, BN=256, wave tile 64x64 (8 waves 2m x 4n), BK=32, 32 K-tiles.
// 3-slot LDS ring (24KB/slot, 72KB) -> 2 blocks/CU. H read from the chunk
// buffer hgen just wrote -> L3-resident. Output stores are NONTEMPORAL:
// 288 MB of write-once data no longer evicts H from L3.
__global__ __launch_bounds__(512, 4) void gemm_pk(
        const short* __restrict__ Hp,   // [mb_cnt*32 units][4096 shorts]
        const short* __restrict__ W2p,  // [4*32 units][8192 shorts]
        const float* __restrict__ b2,
        float* __restrict__ out,        // [M_TOT][V_]
        int mb_base)
{
    __shared__ __align__(16) char lds[3 * 24576];

    const int tid = threadIdx.x;
    const int lane = tid & 63;
    const int w = tid >> 6;            // 0..7
    const int wm = w >> 2, wn = w & 3; // 2m x 4n
    const int l15 = lane & 15, ksel = lane >> 4;

    const int nwg = gridDim.x;
    int bid = blockIdx.x;
    int q = nwg >> 3, r = nwg & 7;
    int xcd = bid & 7, lq = bid >> 3;
    int wg = (xcd < r ? xcd * (q + 1) : r * (q + 1) + (xcd - r) * q) + lq;
    const int mbl = wg >> 2;           // local mb
    const int nb = wg & 3;
    const int m0 = (mb_base + mbl) * 128, n0 = nb * 256;

    const int sr = tid >> 2;
    const int sg = (tid & 3) ^ ((sr >> 1) & 3);
    const short* aU = Hp + (long)mbl * 32 * 4096 + sr * 32 + sg * 8;
    const short* bU = W2p + (long)nb * 32 * 8192 + sr * 32 + sg * 8;
    char* const ldsw = (char*)lds + (w << 10);

#define STAGE_A(t_, sl_) gl_lds16(aU + (long)(t_) * 4096, ldsw + (sl_) * 24576)
#define STAGE_B(t_, sl_) do {                                               \
    char* db_ = ldsw + (sl_) * 24576 + 8192;                                \
    gl_lds16(bU + (long)(t_) * 8192, db_);                                  \
    gl_lds16(bU + (long)(t_) * 8192 + 4096, db_ + 8192);                    \
} while (0)

    f32x4 acc[4][4] = {};
    short8 af[4], bf[4];

#define PH_A(sl_, DOSTAGE, t2_, ss_) do {                                   \
    const char* Ab_ = (const char*)lds + (sl_) * 24576;                     \
    const char* Bb_ = Ab_ + 8192;                                           \
    _Pragma("unroll")                                                       \
    for (int nf = 0; nf < 2; ++nf) {                                        \
        int rw = wn * 64 + nf * 16 + l15;                                   \
        bf[nf] = *(const short8*)(Bb_ + rw * 64 + ((ksel ^ ((rw >> 1) & 3)) << 4)); \
    }                                                                       \
    _Pragma("unroll")                                                       \
    for (int mf = 0; mf < 4; ++mf) {                                        \
        int rw = wm * 64 + mf * 16 + l15;                                   \
        af[mf] = *(const short8*)(Ab_ + rw * 64 + ((ksel ^ ((rw >> 1) & 3)) << 4)); \
    }                                                                       \
    if (DOSTAGE) STAGE_A(t2_, ss_);                                         \
    __builtin_amdgcn_s_barrier();                                           \
    asm volatile("s_waitcnt lgkmcnt(0)" ::: "memory");                      \
    __builtin_amdgcn_s_setprio(1);                                          \
    _Pragma("unroll")                                                       \
    for (int nf = 0; nf < 2; ++nf)                                          \
        _Pragma("unroll")                                                   \
        for (int mf = 0; mf < 4; ++mf)                                      \
            acc[mf][nf] = __builtin_amdgcn_mfma_f32_16x16x32_bf16(          \
                af[mf], bf[nf], acc[mf][nf], 0, 0, 0);                      \
    __builtin_amdgcn_s_setprio(0);                                          \
    __builtin_amdgcn_s_barrier();                                           \
} while (0)

#define PH_B(sl_, DOSTAGE, t2_, ss_, GATE) do {                             \
    const char* Ab_ = (const char*)lds + (sl_) * 24576;                     \
    const char* Bb_ = Ab_ + 8192;                                           \
    _Pragma("unroll")                                                       \
    for (int nf = 2; nf < 4; ++nf) {                                        \
        int rw = wn * 64 + nf * 16 + l15;                                   \
        bf[nf] = *(const short8*)(Bb_ + rw * 64 + ((ksel ^ ((rw >> 1) & 3)) << 4)); \
    }                                                                       \
    if (DOSTAGE) STAGE_B(t2_, ss_);                                         \
    GATE                                                                    \
    __builtin_amdgcn_s_barrier();                                           \
    asm volatile("s_waitcnt lgkmcnt(0)" ::: "memory");                      \
    __builtin_amdgcn_s_setprio(1);                                          \
    _Pragma("unroll")                                                       \
    for (int nf = 2; nf < 4; ++nf)                                          \
        _Pragma("unroll")                                                   \
        for (int mf = 0; mf < 4; ++mf)                                      \
            acc[mf][nf] = __builtin_amdgcn_mfma_f32_16x16x32_bf16(          \
                af[mf], bf[nf], acc[mf][nf], 0, 0, 0);                      \
    __builtin_amdgcn_s_setprio(0);                                          \
    __builtin_amdgcn_s_barrier();                                           \
} while (0)

#define GATE3 asm volatile("s_waitcnt vmcnt(3)" ::: "memory");
#define GATE0 asm volatile("s_waitcnt vmcnt(0)" ::: "memory");
#define NOGATE

    STAGE_A(0, 0); STAGE_B(0, 0);
    STAGE_A(1, 1); STAGE_B(1, 1);
    asm volatile("s_waitcnt vmcnt(3)" ::: "memory");
    __builtin_amdgcn_s_barrier();

    int s = 0, ss = 2;
#pragma unroll 1
    for (int t = 0; t < 30; ++t) {
        PH_A(s, true, t + 2, ss);
        PH_B(s, true, t + 2, ss, GATE3);
        s = (s == 2) ? 0 : s + 1;
        ss = (ss == 2) ? 0 : ss + 1;
    }
    PH_A(s, false, 0, 0); PH_B(s, false, 0, 0, GATE0);
    s = (s == 2) ? 0 : s + 1;
    PH_A(s, false, 0, 0); PH_B(s, false, 0, 0, NOGATE);

    // epilogue: + b2, NONTEMPORAL fp32 stores (write-once data bypasses
    // cache retention -> H stays L3-resident for the co-running blocks)
#pragma unroll
    for (int nf = 0; nf < 4; ++nf) {
        int n = n0 + wn * 64 + nf * 16 + l15;
        if (n < V_) {
            float bv = b2[n];
#pragma unroll
            for (int mf = 0; mf < 4; ++mf)
#pragma unroll
                for (int j = 0; j < 4; ++j) {
                    int m = m0 + wm * 64 + mf * 16 + ksel * 4 + j;
                    if (m < M_TOT)
                        __builtin_nontemporal_store(acc[mf][nf][j] + bv,
                                                    &out[(long)m * V_ + n]);
                }
        }
    }
#undef PH_A
#undef PH_B
#undef STAGE_A
#undef STAGE_B
#undef GATE3
#undef GATE0
#undef NOGATE
}

// ---------------- launch ----------------
extern "C" void kernel_launch(void* const* d_in, const int* in_sizes, int n_in,
                              void* d_out, int out_size, void* d_ws, size_t ws_size,
                              hipStream_t stream) {
    const float* enc = (const float*)d_in[0];
    const float* dec = (const float*)d_in[1];
    const float* W1  = (const float*)d_in[2];
    const float* b1  = (const float*)d_in[3];
    const float* W2  = (const float*)d_in[4];
    const float* b2  = (const float*)d_in[5];
    float* out = (float*)d_out;

    char* ws = (char*)d_ws;
    size_t off = 0;
    short* W1t  = (short*)(ws + off); off += (size_t)1024 * WK * 2;          // 2.06 MB
    short* W2p  = (short*)(ws + off); off += (size_t)4 * 32 * 8192 * 2;      // 2.00 MB
    short* encB = (short*)(ws + off); off += (size_t)1216 * 1024 * 2;        // 2.49 MB
    short* decB = (short*)(ws + off); off += (size_t)256 * 1024 * 2;         // 0.52 MB
    short* Hp   = (short*)(ws + off);                                        // 74 MB (reused per chunk)

    prep_weights<<<dim3(16, 16, 2), 256, 0, stream>>>(W1, W2, W1t, W2p);
    proj_both<<<dim3(23, 16), 256, 0, stream>>>(enc, dec, W1t, b1, encB, decB);

    // chunk 0: mb 0..281 ; chunk 1: mb 282..562 — H stays L3-resident
    hgen_pk<<<CH0 * 64, 256, 0, stream>>>(encB, decB, Hp, 0);
    gemm_pk<<<CH0 * 4, 512, 0, stream>>>(Hp, W2p, b2, out, 0);
    hgen_pk<<<CH1 * 64, 256, 0, stream>>>(encB, decB, Hp, CH0);
    gemm_pk<<<CH1 * 4, 512, 0, stream>>>(Hp, W2p, b2, out, CH0);
}